// Round 4
// baseline (225.398 us; speedup 1.0000x reference)
//
#include <hip/hip_runtime.h>
#include <stdint.h>

#define HNUM 240
#define WNUM 1216
#define BNUM 4
#define HWN (HNUM * WNUM)
#define NPIX (BNUM * HWN)
#define NP2 (NPIX / 2)
#define NP4 (NPIX / 4)
#define WP (WNUM + 3)
#define HP (HNUM + 3)
#define PLANE (HP * WP)
#define NPLANE (BNUM * PLANE)

union HCV { uint32_t u; _Float16 h[2]; };

__device__ __forceinline__ float fast_tanh(float x) {
    float ax = fabsf(x);
    float e  = __builtin_amdgcn_exp2f(ax * 2.885390081777927f);  // 2*log2(e)
    float t  = 1.0f - 2.0f * __builtin_amdgcn_rcpf(e + 1.0f);
    return copysignf(t, x);
}

// one bilinear tap on the pair-plane: cells are (ff[y][x], ff[y+1][x]) as 2xfp16
__device__ __forceinline__ void tap_pair(uint32_t m, float a,
                                         const uint32_t* __restrict__ base,
                                         float& acc) {
    int   rel = (int)(int16_t)(m & 0xffffu);
    float wy  = (float)((m >> 16) & 0xffu) * (1.0f / 255.0f);
    float wx  = (float)(m >> 24)           * (1.0f / 255.0f);
    const uint32_t* q = base + rel;
    HCV c0, c1;
    c0.u = q[0];          // (g00, g10)
    c1.u = q[1];          // (g01, g11)
    float g00 = (float)c0.h[0], g10 = (float)c0.h[1];
    float g01 = (float)c1.h[0], g11 = (float)c1.h[1];
    float top = fmaf(wx, g01 - g00, g00);
    float bot = fmaf(wx, g11 - g10, g10);
    acc = fmaf(a, fmaf(wy, bot - top, top), acc);
}

// build one packed tap word; zeroes aff if tap has no bilinear support
__device__ __forceinline__ uint32_t build_tap(int h, int w, int dy, int dx,
                                              float offy, float offx, float& a) {
    float ys  = (float)(h + dy) + offy;
    float xs  = (float)(w + dx) + offx;
    float y0f = floorf(ys), x0f = floorf(xs);
    int   y0  = (int)y0f,  x0  = (int)x0f;
    float wy  = ys - y0f,  wx  = xs - x0f;
    uint32_t qy = (uint32_t)(wy * 255.0f + 0.5f); if (qy > 255) qy = 255;
    uint32_t qx = (uint32_t)(wx * 255.0f + 0.5f); if (qx > 255) qx = 255;
    bool valid = (y0 >= -1) & (y0 <= HNUM) & (x0 >= -1) & (x0 <= WNUM);
    int rel = (y0 - h) * WP + (x0 - w);
    if (!valid || rel < -32768 || rel > 32767) { rel = 0; qy = 0; qx = 0; a = 0.f; }
    return (uint32_t)(uint16_t)(int16_t)rel | (qy << 16) | (qx << 24);
}

// ---------------------------------------------------------------------------
// init: pair-plane A = (pc[h][w], pc[h+1][w]) padded with zeros; B zeroed.
// ---------------------------------------------------------------------------
__global__ __launch_bounds__(256) void nlspn_init_pad(
    const float* __restrict__ pred,
    const float* __restrict__ conf,
    uint32_t* __restrict__ planeA,
    uint32_t* __restrict__ planeB)
{
    int i = blockIdx.x * blockDim.x + threadIdx.x;
    if (i >= NPLANE) return;
    int b    = i / PLANE;
    int cell = i - b * PLANE;
    int ph   = cell / WP;
    int pw   = cell - ph * WP;
    int w = pw - 1;
    float lo = 0.f, hi = 0.f;
    if (w >= 0 && w < WNUM) {
        int hlo = ph - 1;
        if (hlo >= 0 && hlo < HNUM) {
            int p = b * HWN + hlo * WNUM + w;
            lo = pred[p] * conf[p];
        }
        if (ph < HNUM) {
            int p = b * HWN + ph * WNUM + w;
            hi = pred[p] * conf[p];
        }
    }
    HCV cv; cv.h[0] = (_Float16)lo; cv.h[1] = (_Float16)hi;
    planeA[i] = cv.u;
    planeB[i] = 0u;
}

// ---------------------------------------------------------------------------
// step 1 fused with meta build, 2 px/thread, float2 input loads.
// ---------------------------------------------------------------------------
__global__ __launch_bounds__(256) void nlspn_step1_build(
    const float* __restrict__ aff_raw,
    const float* __restrict__ offset,
    const float* __restrict__ conf,
    const float* __restrict__ dep,
    const float* __restrict__ scale,
    const uint32_t* __restrict__ ffpad_in,
    _Float16* __restrict__ ffpad_out,    // pair-plane viewed as fp16[2*cell]
    uint4* __restrict__ tapsA,
    uint4* __restrict__ tapsB,
    uint4* __restrict__ affv,
    uint2* __restrict__ auxv)
{
    int t = blockIdx.x * blockDim.x + threadIdx.x;
    if (t >= NP2) return;
    int p0 = 2 * t;
    int b  = p0 / HWN;
    int hw = p0 - b * HWN;
    int h  = hw / WNUM;
    int w  = hw - h * WNUM;          // even; px1 = (h, w+1)

    float s    = scale[0];
    float invs = 1.0f / (s + 1e-8f);

    const float2* ar = (const float2*)(aff_raw + (size_t)b * 8 * HWN) + (hw >> 1);
    float a[2][8];
    float asum0 = 0.f, asum1 = 0.f;
#pragma unroll
    for (int k = 0; k < 8; ++k) {
        float2 v = ar[(size_t)k * (HWN / 2)];
        float t0 = fast_tanh(v.x) * invs;
        float t1 = fast_tanh(v.y) * invs;
        a[0][k] = t0; a[1][k] = t1;
        asum0 += fabsf(t0); asum1 += fabsf(t1);
    }
    float aref[2];
    {
        float r0 = 1.0f / fmaxf(asum0 + 1e-4f, 1.0f);
        float r1 = 1.0f / fmaxf(asum1 + 1e-4f, 1.0f);
        float sm0 = 0.f, sm1 = 0.f;
#pragma unroll
        for (int k = 0; k < 8; ++k) {
            a[0][k] *= r0; sm0 += a[0][k];
            a[1][k] *= r1; sm1 += a[1][k];
        }
        aref[0] = 1.0f - sm0;
        aref[1] = 1.0f - sm1;
    }

    const uint32_t* plane = ffpad_in + (size_t)b * PLANE;
    int bp = (h + 1) * WP + (w + 1);
    const uint32_t* base0 = plane + bp;
    const uint32_t* base1 = plane + bp + 1;
    HCV cc;
    cc.u = base0[0]; float acc0 = aref[0] * (float)cc.h[0];
    cc.u = base1[0]; float acc1 = aref[1] * (float)cc.h[0];

    const float2* off = (const float2*)(offset + (size_t)b * 16 * HWN) + (hw >> 1);
    uint32_t tw[2][8];
#pragma unroll
    for (int k = 0; k < 8; ++k) {
        int k9 = (k < 4) ? k : k + 1;
        int dy = k9 / 3 - 1;
        int dx = k9 - (k9 / 3) * 3 - 1;
        float2 oy = off[(size_t)(2 * k)     * (HWN / 2)];
        float2 ox = off[(size_t)(2 * k + 1) * (HWN / 2)];
        uint32_t m0 = build_tap(h, w,     dy, dx, oy.x, ox.x, a[0][k]);
        uint32_t m1 = build_tap(h, w + 1, dy, dx, oy.y, ox.y, a[1][k]);
        tw[0][k] = m0;
        tw[1][k] = m1;
        tap_pair(m0, a[0][k], base0, acc0);
        tap_pair(m1, a[1][k], base1, acc1);
    }

    tapsA[p0]     = make_uint4(tw[0][0], tw[0][1], tw[0][2], tw[0][3]);
    tapsB[p0]     = make_uint4(tw[0][4], tw[0][5], tw[0][6], tw[0][7]);
    tapsA[p0 + 1] = make_uint4(tw[1][0], tw[1][1], tw[1][2], tw[1][3]);
    tapsB[p0 + 1] = make_uint4(tw[1][4], tw[1][5], tw[1][6], tw[1][7]);

    HCV cv;
#pragma unroll
    for (int j = 0; j < 2; ++j) {
        uint32_t aw[4];
#pragma unroll
        for (int k = 0; k < 4; ++k) {
            cv.h[0] = (_Float16)a[j][2 * k];
            cv.h[1] = (_Float16)a[j][2 * k + 1];
            aw[k] = cv.u;
        }
        affv[p0 + j] = make_uint4(aw[0], aw[1], aw[2], aw[3]);
    }

    float2 dd = *(const float2*)(dep  + p0);
    float2 cf = *(const float2*)(conf + p0);

    cv.h[0] = (_Float16)aref[0]; cv.h[1] = (_Float16)cf.x;
    auxv[p0]     = make_uint2(cv.u, __float_as_uint(dd.x));
    cv.h[0] = (_Float16)aref[1]; cv.h[1] = (_Float16)cf.y;
    auxv[p0 + 1] = make_uint2(cv.u, __float_as_uint(dd.y));

    float feat0 = (dd.x > 0.f) ? dd.x : acc0;
    float feat1 = (dd.y > 0.f) ? dd.y : acc1;
    _Float16 o0 = (_Float16)(feat0 * cf.x);
    _Float16 o1 = (_Float16)(feat1 * cf.y);

    size_t gc = (size_t)b * PLANE + bp;
    ffpad_out[2 * gc]                 = o0;   // cell(h+1,w+1).lo
    ffpad_out[2 * (gc - WP) + 1]      = o0;   // cell(h,  w+1).hi
    ffpad_out[2 * (gc + 1)]           = o1;
    ffpad_out[2 * (gc + 1 - WP) + 1]  = o1;
}

// ---------------------------------------------------------------------------
// lean propagation step, 4 px/thread, pair-plane gathers
// ---------------------------------------------------------------------------
template <bool LAST>
__global__ __launch_bounds__(256) void nlspn_prop_meta(
    const uint4* __restrict__ tapsA,
    const uint4* __restrict__ tapsB,
    const uint4* __restrict__ affv,
    const uint4* __restrict__ aux4,      // uint2 aux viewed as uint4 per px-pair
    const uint32_t* __restrict__ ffin,
    _Float16* __restrict__ ffout,
    float* __restrict__ out)
{
    int t = blockIdx.x * blockDim.x + threadIdx.x;
    if (t >= NP4) return;
    int p0 = 4 * t;
    int b  = p0 / HWN;
    int hw = p0 - b * HWN;
    int h  = hw / WNUM;
    int w  = hw - h * WNUM;          // w..w+3 in same row

    const uint32_t* plane = ffin + (size_t)b * PLANE;
    int bp = (h + 1) * WP + (w + 1);

    uint4 tA[4], tB[4], av[4];
#pragma unroll
    for (int j = 0; j < 4; ++j) {
        tA[j] = tapsA[p0 + j];
        tB[j] = tapsB[p0 + j];
        av[j] = affv[p0 + j];
    }
    uint4 x0 = aux4[2 * t];
    uint4 x1 = aux4[2 * t + 1];

    HCV cv;
    float aref[4], cfv[4], dv[4];
    cv.u = x0.x; aref[0] = (float)cv.h[0]; cfv[0] = (float)cv.h[1];
    dv[0] = __uint_as_float(x0.y);
    cv.u = x0.z; aref[1] = (float)cv.h[0]; cfv[1] = (float)cv.h[1];
    dv[1] = __uint_as_float(x0.w);
    cv.u = x1.x; aref[2] = (float)cv.h[0]; cfv[2] = (float)cv.h[1];
    dv[2] = __uint_as_float(x1.y);
    cv.u = x1.z; aref[3] = (float)cv.h[0]; cfv[3] = (float)cv.h[1];
    dv[3] = __uint_as_float(x1.w);

    float acc[4];
#pragma unroll
    for (int j = 0; j < 4; ++j) {
        const uint32_t* base = plane + bp + j;
        cv.u = base[0];
        acc[j] = aref[j] * (float)cv.h[0];
        uint32_t tm[8] = {tA[j].x, tA[j].y, tA[j].z, tA[j].w,
                          tB[j].x, tB[j].y, tB[j].z, tB[j].w};
        float aj[8];
        HCV hv;
        hv.u = av[j].x; aj[0] = (float)hv.h[0]; aj[1] = (float)hv.h[1];
        hv.u = av[j].y; aj[2] = (float)hv.h[0]; aj[3] = (float)hv.h[1];
        hv.u = av[j].z; aj[4] = (float)hv.h[0]; aj[5] = (float)hv.h[1];
        hv.u = av[j].w; aj[6] = (float)hv.h[0]; aj[7] = (float)hv.h[1];
#pragma unroll
        for (int k = 0; k < 8; ++k)
            tap_pair(tm[k], aj[k], base, acc[j]);
    }

    if (LAST) {
        float4 o;
        o.x = (dv[0] > 0.f) ? dv[0] : acc[0];
        o.y = (dv[1] > 0.f) ? dv[1] : acc[1];
        o.z = (dv[2] > 0.f) ? dv[2] : acc[2];
        o.w = (dv[3] > 0.f) ? dv[3] : acc[3];
        *(float4*)(out + p0) = o;
    } else {
        size_t gc = (size_t)b * PLANE + bp;
#pragma unroll
        for (int j = 0; j < 4; ++j) {
            float feat = (dv[j] > 0.f) ? dv[j] : acc[j];
            _Float16 o = (_Float16)(feat * cfv[j]);
            ffout[2 * (gc + j)]          = o;   // .lo of own cell
            ffout[2 * (gc + j - WP) + 1] = o;   // .hi of cell one row up
        }
    }
}

// ---------------------------------------------------------------------------
// fallback (round-1 style) if workspace is too small
// ---------------------------------------------------------------------------
__global__ __launch_bounds__(256) void nlspn_init_kernel(
    const float* __restrict__ pred,
    const float* __restrict__ conf,
    float* __restrict__ ff)
{
    int p = blockIdx.x * blockDim.x + threadIdx.x;
    if (p < NPIX) ff[p] = pred[p] * conf[p];
}

template <bool LAST>
__global__ __launch_bounds__(256) void nlspn_prop_kernel(
    const float* __restrict__ aff_raw,
    const float* __restrict__ offset,
    const float* __restrict__ conf,
    const float* __restrict__ dep,
    const float* __restrict__ scale,
    const float* __restrict__ ff_in,
    float* __restrict__ out)
{
    int p = blockIdx.x * blockDim.x + threadIdx.x;
    if (p >= NPIX) return;
    int b  = p / HWN;
    int hw = p - b * HWN;
    int h  = hw / WNUM;
    int w  = hw - h * WNUM;

    float s    = scale[0];
    float invs = 1.0f / (s + 1e-8f);

    float a[8];
    const float* ar = aff_raw + (size_t)b * 8 * HWN + hw;
#pragma unroll
    for (int k = 0; k < 8; ++k) a[k] = ar[(size_t)k * HWN];

    float asum = 0.0f;
#pragma unroll
    for (int k = 0; k < 8; ++k) {
        a[k] = fast_tanh(a[k]) * invs;
        asum += fabsf(a[k]);
    }
    asum += 1e-4f;
    float rden = 1.0f / fmaxf(asum, 1.0f);
    float suma = 0.0f;
#pragma unroll
    for (int k = 0; k < 8; ++k) { a[k] *= rden; suma += a[k]; }
    float aref = 1.0f - suma;

    const float* ffb = ff_in + (size_t)b * HWN;
    float acc = aref * ffb[hw];

    const float* off = offset + (size_t)b * 16 * HWN + hw;
#pragma unroll
    for (int k = 0; k < 8; ++k) {
        int   k9 = (k < 4) ? k : k + 1;
        int   dy = k9 / 3 - 1;
        int   dx = k9 - (k9 / 3) * 3 - 1;
        float offy = off[(size_t)(2 * k)     * HWN];
        float offx = off[(size_t)(2 * k + 1) * HWN];
        float ysf = (float)(h + dy) + offy;
        float xsf = (float)(w + dx) + offx;
        float y0f = floorf(ysf);
        float x0f = floorf(xsf);
        float wy  = ysf - y0f;
        float wx  = xsf - x0f;
        int   y0  = (int)y0f;
        int   x0  = (int)x0f;
        bool yv0 = (y0 >= 0)  & (y0 < HNUM);
        bool yv1 = (y0 >= -1) & (y0 + 1 < HNUM);
        bool xv0 = (x0 >= 0)  & (x0 < WNUM);
        bool xv1 = (x0 >= -1) & (x0 + 1 < WNUM);
        int row0 = y0 * WNUM;
        float g00 = 0.f, g01 = 0.f, g10 = 0.f, g11 = 0.f;
        if (yv0 & xv0) g00 = ffb[row0 + x0];
        if (yv0 & xv1) g01 = ffb[row0 + x0 + 1];
        if (yv1 & xv0) g10 = ffb[row0 + WNUM + x0];
        if (yv1 & xv1) g11 = ffb[row0 + WNUM + x0 + 1];
        float sampled = (1.f - wy) * ((1.f - wx) * g00 + wx * g01)
                      +        wy  * ((1.f - wx) * g10 + wx * g11);
        acc += a[k] * sampled;
    }

    float dd   = dep[p];
    float feat = (dd > 0.0f) ? dd : acc;
    if (LAST) out[p] = feat;
    else      out[p] = feat * conf[p];
}

// ---------------------------------------------------------------------------
extern "C" void kernel_launch(void* const* d_in, const int* in_sizes, int n_in,
                              void* d_out, int out_size, void* d_ws, size_t ws_size,
                              hipStream_t stream)
{
    const float* aff_raw = (const float*)d_in[0];
    const float* offset  = (const float*)d_in[1];
    const float* conf    = (const float*)d_in[2];
    const float* pred    = (const float*)d_in[3];
    const float* dep     = (const float*)d_in[4];
    const float* scale   = (const float*)d_in[5];
    float* out = (float*)d_out;

    const int threads = 256;
    const int blocksP  = (NPIX + threads - 1) / threads;
    const int blocksS1 = (NP2 + threads - 1) / threads;
    const int blocks4  = (NP4 + threads - 1) / threads;
    const int blocksI  = (NPLANE + threads - 1) / threads;

    const size_t need = (size_t)NPIX * 56 + (size_t)NPLANE * 8 + 64;

    if (ws_size >= need) {
        char* wb = (char*)d_ws;
        uint4* tapsA = (uint4*)wb;  wb += (size_t)NPIX * 16;
        uint4* tapsB = (uint4*)wb;  wb += (size_t)NPIX * 16;
        uint4* affv  = (uint4*)wb;  wb += (size_t)NPIX * 16;
        uint2* auxv  = (uint2*)wb;  wb += (size_t)NPIX * 8;
        uint32_t* plA = (uint32_t*)wb;  wb += (size_t)NPLANE * 4;
        uint32_t* plB = (uint32_t*)wb;
        const uint4* aux4 = (const uint4*)auxv;

        nlspn_init_pad<<<blocksI, threads, 0, stream>>>(pred, conf, plA, plB);
        nlspn_step1_build<<<blocksS1, threads, 0, stream>>>(
            aff_raw, offset, conf, dep, scale, plA, (_Float16*)plB,
            tapsA, tapsB, affv, auxv);                                      // ff1 -> B
        nlspn_prop_meta<false><<<blocks4, threads, 0, stream>>>(
            tapsA, tapsB, affv, aux4, plB, (_Float16*)plA, out);            // ff2 -> A
        nlspn_prop_meta<false><<<blocks4, threads, 0, stream>>>(
            tapsA, tapsB, affv, aux4, plA, (_Float16*)plB, out);            // ff3 -> B
        nlspn_prop_meta<false><<<blocks4, threads, 0, stream>>>(
            tapsA, tapsB, affv, aux4, plB, (_Float16*)plA, out);            // ff4 -> A
        nlspn_prop_meta<false><<<blocks4, threads, 0, stream>>>(
            tapsA, tapsB, affv, aux4, plA, (_Float16*)plB, out);            // ff5 -> B
        nlspn_prop_meta<true><<<blocks4, threads, 0, stream>>>(
            tapsA, tapsB, affv, aux4, plB, (_Float16*)plA, out);            // feat6 -> d_out
    } else {
        float* ws = (float*)d_ws;
        nlspn_init_kernel<<<blocksP, threads, 0, stream>>>(pred, conf, out);
        nlspn_prop_kernel<false><<<blocksP, threads, 0, stream>>>(aff_raw, offset, conf, dep, scale, out, ws);
        nlspn_prop_kernel<false><<<blocksP, threads, 0, stream>>>(aff_raw, offset, conf, dep, scale, ws, out);
        nlspn_prop_kernel<false><<<blocksP, threads, 0, stream>>>(aff_raw, offset, conf, dep, scale, out, ws);
        nlspn_prop_kernel<false><<<blocksP, threads, 0, stream>>>(aff_raw, offset, conf, dep, scale, ws, out);
        nlspn_prop_kernel<false><<<blocksP, threads, 0, stream>>>(aff_raw, offset, conf, dep, scale, out, ws);
        nlspn_prop_kernel<true ><<<blocksP, threads, 0, stream>>>(aff_raw, offset, conf, dep, scale, ws, out);
    }
}

// Round 5
// 168.154 us; speedup vs baseline: 1.3404x; 1.3404x over previous
//
#include <hip/hip_runtime.h>
#include <stdint.h>

#define HNUM 240
#define WNUM 1216
#define BNUM 4
#define HWN (HNUM * WNUM)
#define NPIX (BNUM * HWN)
#define NP2 (NPIX / 2)
#define WP (WNUM + 3)
#define HP (HNUM + 3)
#define PLANE (HP * WP)
#define PP ((PLANE + 15) & ~15)      /* even, dword-aligned per-batch pitch */
#define NPP (BNUM * PP)
#define NXCD 8
#define GRID2 (NP2 / 256)            /* 2280, divisible by 8 */
#define CHUNK2 (GRID2 / NXCD)        /* 285 */

union HCV { uint32_t u; _Float16 h[2]; };

__device__ __forceinline__ float fast_tanh(float x) {
    float ax = fabsf(x);
    float e  = __builtin_amdgcn_exp2f(ax * 2.885390081777927f);  // 2*log2(e)
    float t  = 1.0f - 2.0f * __builtin_amdgcn_rcpf(e + 1.0f);
    return copysignf(t, x);
}

// dual-plane bilinear tap.
// pEv = dword view of natural plane (P0), pOd = dword view of +1-shifted plane (P1).
// afp = batch-local fp16 index of the center cell. WP is odd, so row+1 flips parity.
__device__ __forceinline__ void tap_dual(uint32_t m, float a,
                                         const uint32_t* __restrict__ pEv,
                                         const uint32_t* __restrict__ pOd,
                                         int afp, float& acc) {
    int   rel = (int)(int16_t)(m & 0xffffu);
    float wy  = (float)((m >> 16) & 0xffu) * (1.0f / 255.0f);
    float wx  = (float)(m >> 24)           * (1.0f / 255.0f);
    int a0 = afp + rel;
    int a1 = a0 + WP;
    const uint32_t* r0 = (a0 & 1) ? pOd : pEv;
    const uint32_t* r1 = (a0 & 1) ? pEv : pOd;
    HCV c0, c1;
    c0.u = r0[a0 >> 1];   // (g00, g01)
    c1.u = r1[a1 >> 1];   // (g10, g11)
    float g00 = (float)c0.h[0], g01 = (float)c0.h[1];
    float g10 = (float)c1.h[0], g11 = (float)c1.h[1];
    float top = fmaf(wx, g01 - g00, g00);
    float bot = fmaf(wx, g11 - g10, g10);
    acc = fmaf(a, fmaf(wy, bot - top, top), acc);
}

// build one packed tap word; zeroes aff if tap has no bilinear support
__device__ __forceinline__ uint32_t build_tap(int h, int w, int dy, int dx,
                                              float offy, float offx, float& a) {
    float ys  = (float)(h + dy) + offy;
    float xs  = (float)(w + dx) + offx;
    float y0f = floorf(ys), x0f = floorf(xs);
    int   y0  = (int)y0f,  x0  = (int)x0f;
    float wy  = ys - y0f,  wx  = xs - x0f;
    uint32_t qy = (uint32_t)(wy * 255.0f + 0.5f); if (qy > 255) qy = 255;
    uint32_t qx = (uint32_t)(wx * 255.0f + 0.5f); if (qx > 255) qx = 255;
    bool valid = (y0 >= -1) & (y0 <= HNUM) & (x0 >= -1) & (x0 <= WNUM);
    int rel = (y0 - h) * WP + (x0 - w);
    if (!valid || rel < -32768 || rel > 32767) { rel = 0; qy = 0; qx = 0; a = 0.f; }
    return (uint32_t)(uint16_t)(int16_t)rel | (qy << 16) | (qx << 24);
}

// ---------------------------------------------------------------------------
// init: A0 = padded pred*conf plane, A1 = same shifted by one fp16; B zeroed.
// ---------------------------------------------------------------------------
__device__ __forceinline__ float cellval(const float* __restrict__ pred,
                                         const float* __restrict__ conf,
                                         int b, int c) {
    int ph = c / WP;
    int pw = c - ph * WP;
    int h = ph - 1, w = pw - 1;
    if (h < 0 || h >= HNUM || w < 0 || w >= WNUM) return 0.f;
    int p = b * HWN + h * WNUM + w;
    return pred[p] * conf[p];
}

__global__ __launch_bounds__(256) void nlspn_init_dual(
    const float* __restrict__ pred,
    const float* __restrict__ conf,
    _Float16* __restrict__ A0,
    _Float16* __restrict__ A1,
    _Float16* __restrict__ B0,
    _Float16* __restrict__ B1)
{
    int i = blockIdx.x * blockDim.x + threadIdx.x;
    if (i >= NPP) return;
    int b = i / PP;
    int c = i - b * PP;
    A0[i] = (_Float16)cellval(pred, conf, b, c);
    A1[i] = (_Float16)((c + 1 < PP) ? cellval(pred, conf, b, c + 1) : 0.f);
    B0[i] = (_Float16)0.f;
    B1[i] = (_Float16)0.f;
}

// ---------------------------------------------------------------------------
// step 1 fused with meta build, 2 px/thread, float2 input loads, dual planes
// ---------------------------------------------------------------------------
__global__ __launch_bounds__(256) void nlspn_step1_build(
    const float* __restrict__ aff_raw,
    const float* __restrict__ offset,
    const float* __restrict__ conf,
    const float* __restrict__ dep,
    const float* __restrict__ scale,
    const _Float16* __restrict__ A0,
    const _Float16* __restrict__ A1,
    _Float16* __restrict__ B0,
    _Float16* __restrict__ B1,
    uint4* __restrict__ tapsA,
    uint4* __restrict__ tapsB,
    uint4* __restrict__ affv,
    uint2* __restrict__ auxv)
{
    int bid = blockIdx.x;
    int nb  = (bid & (NXCD - 1)) * CHUNK2 + (bid >> 3);
    int t   = nb * 256 + (int)threadIdx.x;      // t < NP2 exactly
    int p0 = 2 * t;
    int b  = p0 / HWN;
    int hw = p0 - b * HWN;
    int h  = hw / WNUM;
    int w  = hw - h * WNUM;          // even; px1 = (h, w+1), never wraps

    float s    = scale[0];
    float invs = 1.0f / (s + 1e-8f);

    const float2* ar = (const float2*)(aff_raw + (size_t)b * 8 * HWN) + (hw >> 1);
    float a[2][8];
    float asum0 = 0.f, asum1 = 0.f;
#pragma unroll
    for (int k = 0; k < 8; ++k) {
        float2 v = ar[(size_t)k * (HWN / 2)];
        float t0 = fast_tanh(v.x) * invs;
        float t1 = fast_tanh(v.y) * invs;
        a[0][k] = t0; a[1][k] = t1;
        asum0 += fabsf(t0); asum1 += fabsf(t1);
    }
    float aref[2];
    {
        float r0 = 1.0f / fmaxf(asum0 + 1e-4f, 1.0f);
        float r1 = 1.0f / fmaxf(asum1 + 1e-4f, 1.0f);
        float sm0 = 0.f, sm1 = 0.f;
#pragma unroll
        for (int k = 0; k < 8; ++k) {
            a[0][k] *= r0; sm0 += a[0][k];
            a[1][k] *= r1; sm1 += a[1][k];
        }
        aref[0] = 1.0f - sm0;
        aref[1] = 1.0f - sm1;
    }

    const _Float16* A0b = A0 + (size_t)b * PP;
    const uint32_t* pEv = (const uint32_t*)A0b;
    const uint32_t* pOd = (const uint32_t*)(A1 + (size_t)b * PP);
    int bp = (h + 1) * WP + (w + 1);

    float acc0 = aref[0] * (float)A0b[bp];
    float acc1 = aref[1] * (float)A0b[bp + 1];

    const float2* off = (const float2*)(offset + (size_t)b * 16 * HWN) + (hw >> 1);
    uint32_t tw[2][8];
#pragma unroll
    for (int k = 0; k < 8; ++k) {
        int k9 = (k < 4) ? k : k + 1;
        int dy = k9 / 3 - 1;
        int dx = k9 - (k9 / 3) * 3 - 1;
        float2 oy = off[(size_t)(2 * k)     * (HWN / 2)];
        float2 ox = off[(size_t)(2 * k + 1) * (HWN / 2)];
        uint32_t m0 = build_tap(h, w,     dy, dx, oy.x, ox.x, a[0][k]);
        uint32_t m1 = build_tap(h, w + 1, dy, dx, oy.y, ox.y, a[1][k]);
        tw[0][k] = m0;
        tw[1][k] = m1;
        tap_dual(m0, a[0][k], pEv, pOd, bp,     acc0);
        tap_dual(m1, a[1][k], pEv, pOd, bp + 1, acc1);
    }

    tapsA[p0]     = make_uint4(tw[0][0], tw[0][1], tw[0][2], tw[0][3]);
    tapsB[p0]     = make_uint4(tw[0][4], tw[0][5], tw[0][6], tw[0][7]);
    tapsA[p0 + 1] = make_uint4(tw[1][0], tw[1][1], tw[1][2], tw[1][3]);
    tapsB[p0 + 1] = make_uint4(tw[1][4], tw[1][5], tw[1][6], tw[1][7]);

    HCV cv;
#pragma unroll
    for (int j = 0; j < 2; ++j) {
        uint32_t aw[4];
#pragma unroll
        for (int k = 0; k < 4; ++k) {
            cv.h[0] = (_Float16)a[j][2 * k];
            cv.h[1] = (_Float16)a[j][2 * k + 1];
            aw[k] = cv.u;
        }
        affv[p0 + j] = make_uint4(aw[0], aw[1], aw[2], aw[3]);
    }

    float2 dd = *(const float2*)(dep  + p0);
    float2 cf = *(const float2*)(conf + p0);

    cv.h[0] = (_Float16)aref[0]; cv.h[1] = (_Float16)cf.x;
    auxv[p0]     = make_uint2(cv.u, __float_as_uint(dd.x));
    cv.h[0] = (_Float16)aref[1]; cv.h[1] = (_Float16)cf.y;
    auxv[p0 + 1] = make_uint2(cv.u, __float_as_uint(dd.y));

    float feat0 = (dd.x > 0.f) ? dd.x : acc0;
    float feat1 = (dd.y > 0.f) ? dd.y : acc1;
    _Float16 o0 = (_Float16)(feat0 * cf.x);
    _Float16 o1 = (_Float16)(feat1 * cf.y);

    _Float16* B0b = B0 + (size_t)b * PP;
    _Float16* B1b = B1 + (size_t)b * PP;
    B0b[bp]     = o0;  B1b[bp - 1] = o0;
    B0b[bp + 1] = o1;  B1b[bp]     = o1;
}

// ---------------------------------------------------------------------------
// lean propagation step, 2 px/thread, dual-plane gathers, XCD-chunked blocks
// ---------------------------------------------------------------------------
template <bool LAST>
__global__ __launch_bounds__(256) void nlspn_prop_dual(
    const uint4* __restrict__ tapsA,
    const uint4* __restrict__ tapsB,
    const uint4* __restrict__ affv,
    const uint4* __restrict__ aux4,      // uint2 aux viewed as uint4 per px-pair
    const _Float16* __restrict__ I0,
    const _Float16* __restrict__ I1,
    _Float16* __restrict__ O0,
    _Float16* __restrict__ O1,
    float* __restrict__ out)
{
    int bid = blockIdx.x;
    int nb  = (bid & (NXCD - 1)) * CHUNK2 + (bid >> 3);
    int t   = nb * 256 + (int)threadIdx.x;      // t < NP2 exactly
    int p0 = 2 * t;
    int b  = p0 / HWN;
    int hw = p0 - b * HWN;
    int h  = hw / WNUM;
    int w  = hw - h * WNUM;          // even; pair never wraps a row
    int bp = (h + 1) * WP + (w + 1);

    uint4 tA0 = tapsA[p0];
    uint4 tB0 = tapsB[p0];
    uint4 tA1 = tapsA[p0 + 1];
    uint4 tB1 = tapsB[p0 + 1];
    uint4 av0 = affv[p0];
    uint4 av1 = affv[p0 + 1];
    uint4 ax  = aux4[t];   // {half2(aref0,c0), dep0, half2(aref1,c1), dep1}

    HCV cv;
    float a0[8], a1[8];
    cv.u = av0.x; a0[0] = (float)cv.h[0]; a0[1] = (float)cv.h[1];
    cv.u = av0.y; a0[2] = (float)cv.h[0]; a0[3] = (float)cv.h[1];
    cv.u = av0.z; a0[4] = (float)cv.h[0]; a0[5] = (float)cv.h[1];
    cv.u = av0.w; a0[6] = (float)cv.h[0]; a0[7] = (float)cv.h[1];
    cv.u = av1.x; a1[0] = (float)cv.h[0]; a1[1] = (float)cv.h[1];
    cv.u = av1.y; a1[2] = (float)cv.h[0]; a1[3] = (float)cv.h[1];
    cv.u = av1.z; a1[4] = (float)cv.h[0]; a1[5] = (float)cv.h[1];
    cv.u = av1.w; a1[6] = (float)cv.h[0]; a1[7] = (float)cv.h[1];

    cv.u = ax.x;
    float aref0 = (float)cv.h[0], c0 = (float)cv.h[1];
    float d0 = __uint_as_float(ax.y);
    cv.u = ax.z;
    float aref1 = (float)cv.h[0], c1 = (float)cv.h[1];
    float d1 = __uint_as_float(ax.w);

    const _Float16* I0b = I0 + (size_t)b * PP;
    const uint32_t* pEv = (const uint32_t*)I0b;
    const uint32_t* pOd = (const uint32_t*)(I1 + (size_t)b * PP);

    float acc0 = aref0 * (float)I0b[bp];
    float acc1 = aref1 * (float)I0b[bp + 1];

    uint32_t tm0[8] = {tA0.x, tA0.y, tA0.z, tA0.w, tB0.x, tB0.y, tB0.z, tB0.w};
    uint32_t tm1[8] = {tA1.x, tA1.y, tA1.z, tA1.w, tB1.x, tB1.y, tB1.z, tB1.w};
#pragma unroll
    for (int k = 0; k < 8; ++k) {
        tap_dual(tm0[k], a0[k], pEv, pOd, bp,     acc0);
        tap_dual(tm1[k], a1[k], pEv, pOd, bp + 1, acc1);
    }

    float feat0 = (d0 > 0.f) ? d0 : acc0;
    float feat1 = (d1 > 0.f) ? d1 : acc1;

    if (LAST) {
        *(float2*)(out + p0) = make_float2(feat0, feat1);
    } else {
        _Float16 o0 = (_Float16)(feat0 * c0);
        _Float16 o1 = (_Float16)(feat1 * c1);
        _Float16* O0b = O0 + (size_t)b * PP;
        _Float16* O1b = O1 + (size_t)b * PP;
        O0b[bp]     = o0;  O1b[bp - 1] = o0;
        O0b[bp + 1] = o1;  O1b[bp]     = o1;
    }
}

// ---------------------------------------------------------------------------
// fallback (round-1 style) if workspace is too small
// ---------------------------------------------------------------------------
__global__ __launch_bounds__(256) void nlspn_init_kernel(
    const float* __restrict__ pred,
    const float* __restrict__ conf,
    float* __restrict__ ff)
{
    int p = blockIdx.x * blockDim.x + threadIdx.x;
    if (p < NPIX) ff[p] = pred[p] * conf[p];
}

template <bool LAST>
__global__ __launch_bounds__(256) void nlspn_prop_kernel(
    const float* __restrict__ aff_raw,
    const float* __restrict__ offset,
    const float* __restrict__ conf,
    const float* __restrict__ dep,
    const float* __restrict__ scale,
    const float* __restrict__ ff_in,
    float* __restrict__ out)
{
    int p = blockIdx.x * blockDim.x + threadIdx.x;
    if (p >= NPIX) return;
    int b  = p / HWN;
    int hw = p - b * HWN;
    int h  = hw / WNUM;
    int w  = hw - h * WNUM;

    float s    = scale[0];
    float invs = 1.0f / (s + 1e-8f);

    float a[8];
    const float* ar = aff_raw + (size_t)b * 8 * HWN + hw;
#pragma unroll
    for (int k = 0; k < 8; ++k) a[k] = ar[(size_t)k * HWN];

    float asum = 0.0f;
#pragma unroll
    for (int k = 0; k < 8; ++k) {
        a[k] = fast_tanh(a[k]) * invs;
        asum += fabsf(a[k]);
    }
    asum += 1e-4f;
    float rden = 1.0f / fmaxf(asum, 1.0f);
    float suma = 0.0f;
#pragma unroll
    for (int k = 0; k < 8; ++k) { a[k] *= rden; suma += a[k]; }
    float aref = 1.0f - suma;

    const float* ffb = ff_in + (size_t)b * HWN;
    float acc = aref * ffb[hw];

    const float* off = offset + (size_t)b * 16 * HWN + hw;
#pragma unroll
    for (int k = 0; k < 8; ++k) {
        int   k9 = (k < 4) ? k : k + 1;
        int   dy = k9 / 3 - 1;
        int   dx = k9 - (k9 / 3) * 3 - 1;
        float offy = off[(size_t)(2 * k)     * HWN];
        float offx = off[(size_t)(2 * k + 1) * HWN];
        float ysf = (float)(h + dy) + offy;
        float xsf = (float)(w + dx) + offx;
        float y0f = floorf(ysf);
        float x0f = floorf(xsf);
        float wy  = ysf - y0f;
        float wx  = xsf - x0f;
        int   y0  = (int)y0f;
        int   x0  = (int)x0f;
        bool yv0 = (y0 >= 0)  & (y0 < HNUM);
        bool yv1 = (y0 >= -1) & (y0 + 1 < HNUM);
        bool xv0 = (x0 >= 0)  & (x0 < WNUM);
        bool xv1 = (x0 >= -1) & (x0 + 1 < WNUM);
        int row0 = y0 * WNUM;
        float g00 = 0.f, g01 = 0.f, g10 = 0.f, g11 = 0.f;
        if (yv0 & xv0) g00 = ffb[row0 + x0];
        if (yv0 & xv1) g01 = ffb[row0 + x0 + 1];
        if (yv1 & xv0) g10 = ffb[row0 + WNUM + x0];
        if (yv1 & xv1) g11 = ffb[row0 + WNUM + x0 + 1];
        float sampled = (1.f - wy) * ((1.f - wx) * g00 + wx * g01)
                      +        wy  * ((1.f - wx) * g10 + wx * g11);
        acc += a[k] * sampled;
    }

    float dd   = dep[p];
    float feat = (dd > 0.0f) ? dd : acc;
    if (LAST) out[p] = feat;
    else      out[p] = feat * conf[p];
}

// ---------------------------------------------------------------------------
extern "C" void kernel_launch(void* const* d_in, const int* in_sizes, int n_in,
                              void* d_out, int out_size, void* d_ws, size_t ws_size,
                              hipStream_t stream)
{
    const float* aff_raw = (const float*)d_in[0];
    const float* offset  = (const float*)d_in[1];
    const float* conf    = (const float*)d_in[2];
    const float* pred    = (const float*)d_in[3];
    const float* dep     = (const float*)d_in[4];
    const float* scale   = (const float*)d_in[5];
    float* out = (float*)d_out;

    const int threads = 256;
    const int blocksP = (NPIX + threads - 1) / threads;
    const int blocksI = (NPP + threads - 1) / threads;

    const size_t need = (size_t)NPIX * 56 + (size_t)NPP * 2 * 4 + 64;

    if (ws_size >= need) {
        char* wb = (char*)d_ws;
        uint4* tapsA = (uint4*)wb;  wb += (size_t)NPIX * 16;
        uint4* tapsB = (uint4*)wb;  wb += (size_t)NPIX * 16;
        uint4* affv  = (uint4*)wb;  wb += (size_t)NPIX * 16;
        uint2* auxv  = (uint2*)wb;  wb += (size_t)NPIX * 8;
        _Float16* A0 = (_Float16*)wb;  wb += (size_t)NPP * 2;
        _Float16* A1 = (_Float16*)wb;  wb += (size_t)NPP * 2;
        _Float16* B0 = (_Float16*)wb;  wb += (size_t)NPP * 2;
        _Float16* B1 = (_Float16*)wb;
        const uint4* aux4 = (const uint4*)auxv;

        nlspn_init_dual<<<blocksI, threads, 0, stream>>>(pred, conf, A0, A1, B0, B1);
        nlspn_step1_build<<<GRID2, threads, 0, stream>>>(
            aff_raw, offset, conf, dep, scale, A0, A1, B0, B1,
            tapsA, tapsB, affv, auxv);                                      // ff1 -> B
        nlspn_prop_dual<false><<<GRID2, threads, 0, stream>>>(
            tapsA, tapsB, affv, aux4, B0, B1, A0, A1, out);                 // ff2 -> A
        nlspn_prop_dual<false><<<GRID2, threads, 0, stream>>>(
            tapsA, tapsB, affv, aux4, A0, A1, B0, B1, out);                 // ff3 -> B
        nlspn_prop_dual<false><<<GRID2, threads, 0, stream>>>(
            tapsA, tapsB, affv, aux4, B0, B1, A0, A1, out);                 // ff4 -> A
        nlspn_prop_dual<false><<<GRID2, threads, 0, stream>>>(
            tapsA, tapsB, affv, aux4, A0, A1, B0, B1, out);                 // ff5 -> B
        nlspn_prop_dual<true><<<GRID2, threads, 0, stream>>>(
            tapsA, tapsB, affv, aux4, B0, B1, A0, A1, out);                 // feat6 -> d_out
    } else {
        float* ws = (float*)d_ws;
        nlspn_init_kernel<<<blocksP, threads, 0, stream>>>(pred, conf, out);
        nlspn_prop_kernel<false><<<blocksP, threads, 0, stream>>>(aff_raw, offset, conf, dep, scale, out, ws);
        nlspn_prop_kernel<false><<<blocksP, threads, 0, stream>>>(aff_raw, offset, conf, dep, scale, ws, out);
        nlspn_prop_kernel<false><<<blocksP, threads, 0, stream>>>(aff_raw, offset, conf, dep, scale, out, ws);
        nlspn_prop_kernel<false><<<blocksP, threads, 0, stream>>>(aff_raw, offset, conf, dep, scale, ws, out);
        nlspn_prop_kernel<false><<<blocksP, threads, 0, stream>>>(aff_raw, offset, conf, dep, scale, out, ws);
        nlspn_prop_kernel<true ><<<blocksP, threads, 0, stream>>>(aff_raw, offset, conf, dep, scale, ws, out);
    }
}